// Round 5
// baseline (584.241 us; speedup 1.0000x reference)
//
#include <hip/hip_runtime.h>
#include <math.h>

// FFT long conv:  out = circconv_8193(x, h)/8193 masked, h = f + 8193*bias_d*delta.
// Linear conv via FFT-16384, wrap-added: y[n] = z[n] + z[n+8193] (z[16384]=0 edge).
// Two batch rows packed as real+imag of one complex FFT (real filter => no unpack).
// Radix-16 register passes: each LDS round-trip performs TWO radix-4 stages on a
// thread-private closed 16-element set. Fwd: A(st0+st1, fused global load),
// B(st2+st3), C(st4+st5), D(st6 + G-mul + inv-st6 + inv-st5). Inv: E(st4+st3),
// F(st2+st1), G(st0 + wrap-add epilogue). LDS index XOR-swizzle S(i)=i^(i>>5):
// bijective, hits the bank floor for every stride in {1,4,16,64,256,1024,4096}.
// Twiddles generated by v_sin/v_cos (revolutions, first quadrant only, e<4096).

namespace {

constexpr int Hh = 16, Dd = 64, Ll = 8192;
constexpr int HD = Hh * Dd;          // 1024
constexpr int NFFT = 16384;
constexpr int NT = 1024;             // threads per block (16 waves)

#define SW(i) ((i) ^ ((i) >> 5))

__device__ inline float2 cadd(float2 a, float2 b) { return make_float2(a.x + b.x, a.y + b.y); }
__device__ inline float2 csub(float2 a, float2 b) { return make_float2(a.x - b.x, a.y - b.y); }
__device__ inline float2 cmul(float2 a, float2 b) {
  return make_float2(a.x * b.x - a.y * b.y, a.x * b.y + a.y * b.x);
}
__device__ inline float2 cmulc(float2 a, float2 b) {  // a * conj(b)
  return make_float2(a.x * b.x + a.y * b.y, a.y * b.x - a.x * b.y);
}

// w1=w^e, w2=w^2e, w3=w^3e; w = exp(-2*pi*i/16384); requires e in [0,4096)
__device__ inline void tw3(int e, float2& w1, float2& w2, float2& w3) {
  float x = (float)e * (1.0f / 16384.0f);
  w1 = make_float2(__builtin_amdgcn_cosf(x), -__builtin_amdgcn_sinf(x));
  w2 = cmul(w1, w1);
  w3 = cmul(w2, w1);
}

// forward radix-4 DIF butterfly; outputs 1..3 twiddled by w1,w2,w3
__device__ inline void bf4f(float2& x0, float2& x1, float2& x2, float2& x3,
                            float2 w1, float2 w2, float2 w3) {
  float2 t0 = cadd(x0, x2), t1 = csub(x0, x2), t2 = cadd(x1, x3), t3 = csub(x1, x3);
  float2 y0 = cadd(t0, t2), y2 = csub(t0, t2);
  float2 y1 = make_float2(t1.x + t3.y, t1.y - t3.x);   // t1 + (-i)t3
  float2 y3 = make_float2(t1.x - t3.y, t1.y + t3.x);   // t1 - (-i)t3
  x0 = y0; x1 = cmul(y1, w1); x2 = cmul(y2, w2); x3 = cmul(y3, w3);
}
__device__ inline void bf4f_nt(float2& x0, float2& x1, float2& x2, float2& x3) {
  float2 t0 = cadd(x0, x2), t1 = csub(x0, x2), t2 = cadd(x1, x3), t3 = csub(x1, x3);
  float2 y0 = cadd(t0, t2), y2 = csub(t0, t2);
  float2 y1 = make_float2(t1.x + t3.y, t1.y - t3.x);
  float2 y3 = make_float2(t1.x - t3.y, t1.y + t3.x);
  x0 = y0; x1 = y1; x2 = y2; x3 = y3;
}
// inverse radix-4 DIT butterfly; inputs 1..3 un-twiddled by conj(w1..w3)
__device__ inline void bf4i(float2& x0, float2& x1, float2& x2, float2& x3,
                            float2 w1, float2 w2, float2 w3) {
  float2 u1 = cmulc(x1, w1), u2 = cmulc(x2, w2), u3 = cmulc(x3, w3);
  float2 t0 = cadd(x0, u2), t1 = csub(x0, u2), t2 = cadd(u1, u3), t3 = csub(u1, u3);
  x0 = cadd(t0, t2);
  x1 = make_float2(t1.x - t3.y, t1.y + t3.x);          // t1 + i*t3
  x2 = csub(t0, t2);
  x3 = make_float2(t1.x + t3.y, t1.y - t3.x);          // t1 - i*t3
}
__device__ inline void bf4i_nt(float2& x0, float2& x1, float2& x2, float2& x3) {
  float2 t0 = cadd(x0, x2), t1 = csub(x0, x2), t2 = cadd(x1, x3), t3 = csub(x1, x3);
  x0 = cadd(t0, t2);
  x1 = make_float2(t1.x - t3.y, t1.y + t3.x);
  x2 = csub(t0, t2);
  x3 = make_float2(t1.x + t3.y, t1.y - t3.x);
}

// Forward fused pass: stages (ST, ST+1). Element set: base + al*Q + be*(Q/4).
template<int ST>
__device__ inline void fwd_pair(float2* a, int t) {
  constexpr int Q  = 1 << (12 - 2 * ST);
  constexpr int Q4 = Q >> 2;
  const int lo = t & (Q4 - 1);
  const int hi = t >> (10 - 2 * ST);
  const int base = hi * (Q << 2) + lo;
  float2 r[16];
#pragma unroll
  for (int al = 0; al < 4; ++al)
#pragma unroll
    for (int be = 0; be < 4; ++be)
      r[al * 4 + be] = a[SW(base + al * Q + be * Q4)];
#pragma unroll
  for (int be = 0; be < 4; ++be) {             // stage ST over al
    float2 w1, w2, w3; tw3((lo + be * Q4) << (2 * ST), w1, w2, w3);
    bf4f(r[be], r[4 + be], r[8 + be], r[12 + be], w1, w2, w3);
  }
  {                                            // stage ST+1 over be (shared twiddle)
    float2 w1, w2, w3; tw3(lo << (2 * ST + 2), w1, w2, w3);
#pragma unroll
    for (int al = 0; al < 4; ++al)
      bf4f(r[al * 4 + 0], r[al * 4 + 1], r[al * 4 + 2], r[al * 4 + 3], w1, w2, w3);
  }
#pragma unroll
  for (int al = 0; al < 4; ++al)
#pragma unroll
    for (int be = 0; be < 4; ++be)
      a[SW(base + al * Q + be * Q4)] = r[al * 4 + be];
}

// Inverse fused pass: stages (ST, ST-1). Element set: base + al*QA + be*(4*QA).
template<int ST>
__device__ inline void inv_pair(float2* a, int t) {
  constexpr int QA = 1 << (12 - 2 * ST);
  constexpr int QB = QA << 2;
  const int lo = t & (QA - 1);
  const int hi = t >> (12 - 2 * ST);
  const int base = hi * (QA << 4) + lo;
  float2 r[16];
#pragma unroll
  for (int al = 0; al < 4; ++al)
#pragma unroll
    for (int be = 0; be < 4; ++be)
      r[al * 4 + be] = a[SW(base + al * QA + be * QB)];
  {                                            // inv stage ST over al (shared twiddle)
    float2 w1, w2, w3; tw3(lo << (2 * ST), w1, w2, w3);
#pragma unroll
    for (int be = 0; be < 4; ++be)
      bf4i(r[be], r[4 + be], r[8 + be], r[12 + be], w1, w2, w3);
  }
#pragma unroll
  for (int al = 0; al < 4; ++al) {             // inv stage ST-1 over be
    float2 w1, w2, w3; tw3((lo + al * QA) << (2 * ST - 2), w1, w2, w3);
    bf4i(r[al * 4 + 0], r[al * 4 + 1], r[al * 4 + 2], r[al * 4 + 3], w1, w2, w3);
  }
#pragma unroll
  for (int al = 0; al < 4; ++al)
#pragma unroll
    for (int be = 0; be < 4; ++be)
      a[SW(base + al * QA + be * QB)] = r[al * 4 + be];
}

}  // namespace

// Kernel A: per (h,d) row, G = (FFT_16384(h)/8193)/16384 in scrambled order.
__global__ __launch_bounds__(NT, 4) void filt_fft_kernel(const float* __restrict__ filters,
                                                         const float* __restrict__ bias,
                                                         float2* __restrict__ G) {
  __shared__ float2 a[NFFT];
  const int tid = threadIdx.x;
  const int hd = blockIdx.x;
  const int d = hd & (Dd - 1);
  const float sc = 1.0f / (8193.0f * 16384.0f);
  const float* f = filters + (size_t)hd * Ll;
  {  // Pass A: load real (zero-padded: al=2,3 are 0) + st0 + st1
    float2 r[16];
#pragma unroll
    for (int be = 0; be < 4; ++be) {
      int idx = tid + 1024 * be;
      float f0 = f[idx] * sc;
      float f1 = f[idx + 4096] * sc;
      float2 w1, w2, w3; tw3(idx, w1, w2, w3);
      r[be]      = make_float2(f0 + f1, 0.0f);
      r[4 + be]  = cmul(make_float2(f0, -f1), w1);
      r[8 + be]  = cmul(make_float2(f0 - f1, 0.0f), w2);
      r[12 + be] = cmul(make_float2(f0, f1), w3);
    }
    {
      float2 w1, w2, w3; tw3(tid << 2, w1, w2, w3);
#pragma unroll
      for (int al = 0; al < 4; ++al)
        bf4f(r[al * 4 + 0], r[al * 4 + 1], r[al * 4 + 2], r[al * 4 + 3], w1, w2, w3);
    }
#pragma unroll
    for (int al = 0; al < 4; ++al)
#pragma unroll
      for (int be = 0; be < 4; ++be)
        a[SW(tid + al * 4096 + be * 1024)] = r[al * 4 + be];
  }
  __syncthreads();
  fwd_pair<2>(a, tid);
  __syncthreads();
  fwd_pair<4>(a, tid);
  __syncthreads();
  {  // Pass D': st6 (unity twiddles) + bias + store G from registers
    float bd = bias[d] * (1.0f / 16384.0f);
    float4* g4 = reinterpret_cast<float4*>(G + (size_t)hd * NFFT);
#pragma unroll
    for (int m = 0; m < 4; ++m) {
      int i0 = 16 * tid + 4 * m;
      float2 q0 = a[SW(i0)], q1 = a[SW(i0 + 1)], q2 = a[SW(i0 + 2)], q3 = a[SW(i0 + 3)];
      bf4f_nt(q0, q1, q2, q3);
      g4[8 * tid + 2 * m]     = make_float4(q0.x + bd, q0.y, q1.x + bd, q1.y);
      g4[8 * tid + 2 * m + 1] = make_float4(q2.x + bd, q2.y, q3.x + bd, q3.y);
    }
  }
}

// Kernel B: per (batch-pair, h, d): pack 2 rows, FFT, *G, IFFT, wrap-add, mask, store.
__global__ __launch_bounds__(NT, 4) void conv_fft_kernel(const float* __restrict__ inputs,
                                                         const float2* __restrict__ G,
                                                         const int* __restrict__ positions,
                                                         float* __restrict__ out) {
  __shared__ float2 a[NFFT];
  const int tid = threadIdx.x;
  const int blk = blockIdx.x;          // pair*1024 + hd
  const int hd = blk & (HD - 1);
  const int pair = blk >> 10;
  const int b0 = 2 * pair, b1 = b0 + 1;
  const float* r0 = inputs + ((size_t)b0 * HD + hd) * Ll;
  const float* r1 = inputs + ((size_t)b1 * HD + hd) * Ll;
  {  // Pass A: load packed complex (al=2,3 zero) + st0 + st1
    float2 r[16];
#pragma unroll
    for (int be = 0; be < 4; ++be) {
      int idx = tid + 1024 * be;
      r[be]     = make_float2(r0[idx], r1[idx]);
      r[4 + be] = make_float2(r0[idx + 4096], r1[idx + 4096]);
    }
#pragma unroll
    for (int be = 0; be < 4; ++be) {
      float2 x0 = r[be], x1 = r[4 + be];
      float2 w1, w2, w3; tw3(tid + 1024 * be, w1, w2, w3);
      float2 y0 = cadd(x0, x1);
      float2 y2 = csub(x0, x1);
      float2 y1 = make_float2(x0.x + x1.y, x0.y - x1.x);   // x0 - i*x1
      float2 y3 = make_float2(x0.x - x1.y, x0.y + x1.x);   // x0 + i*x1
      r[be]      = y0;
      r[4 + be]  = cmul(y1, w1);
      r[8 + be]  = cmul(y2, w2);
      r[12 + be] = cmul(y3, w3);
    }
    {
      float2 w1, w2, w3; tw3(tid << 2, w1, w2, w3);
#pragma unroll
      for (int al = 0; al < 4; ++al)
        bf4f(r[al * 4 + 0], r[al * 4 + 1], r[al * 4 + 2], r[al * 4 + 3], w1, w2, w3);
    }
#pragma unroll
    for (int al = 0; al < 4; ++al)
#pragma unroll
      for (int be = 0; be < 4; ++be)
        a[SW(tid + al * 4096 + be * 1024)] = r[al * 4 + be];
  }
  __syncthreads();
  // Prefetch G (consumed in pass D) to hide HBM latency under passes B,C.
  const float4* g4 = reinterpret_cast<const float4*>(G + (size_t)hd * NFFT);
  float4 gr[8];
#pragma unroll
  for (int k = 0; k < 8; ++k) gr[k] = g4[8 * tid + k];
  fwd_pair<2>(a, tid);
  __syncthreads();
  fwd_pair<4>(a, tid);
  __syncthreads();
  {  // Pass D: fwd st6 + G-mul + inv st6 (all unity twiddles) + inv st5
    float2 r[16];
#pragma unroll
    for (int m = 0; m < 4; ++m) {
      int i0 = 16 * tid + 4 * m;
      float2 q0 = a[SW(i0)], q1 = a[SW(i0 + 1)], q2 = a[SW(i0 + 2)], q3 = a[SW(i0 + 3)];
      bf4f_nt(q0, q1, q2, q3);
      float4 ga = gr[2 * m], gb = gr[2 * m + 1];
      q0 = cmul(q0, make_float2(ga.x, ga.y));
      q1 = cmul(q1, make_float2(ga.z, ga.w));
      q2 = cmul(q2, make_float2(gb.x, gb.y));
      q3 = cmul(q3, make_float2(gb.z, gb.w));
      bf4i_nt(q0, q1, q2, q3);
      r[4 * m + 0] = q0; r[4 * m + 1] = q1; r[4 * m + 2] = q2; r[4 * m + 3] = q3;
    }
#pragma unroll
    for (int c = 0; c < 4; ++c) {              // inv st5: over quads, j=c
      float2 w1, w2, w3; tw3(c << 10, w1, w2, w3);
      bf4i(r[c], r[4 + c], r[8 + c], r[12 + c], w1, w2, w3);
    }
#pragma unroll
    for (int m = 0; m < 4; ++m)
#pragma unroll
      for (int c = 0; c < 4; ++c)
        a[SW(16 * tid + 4 * m + c)] = r[4 * m + c];
  }
  __syncthreads();
  inv_pair<4>(a, tid);
  __syncthreads();
  inv_pair<2>(a, tid);
  __syncthreads();
  {  // Pass G: inv st0 + wrap-add epilogue
    const int* pos0 = positions + (size_t)b0 * Ll;
    const int* pos1 = positions + (size_t)b1 * Ll;
    float* o0 = out + ((size_t)b0 * HD + hd) * Ll;
    float* o1 = out + ((size_t)b1 * HD + hd) * Ll;
    // prefetch masks early
    int pm[16];
#pragma unroll
    for (int m = 0; m < 4; ++m) {
      int n = tid + 1024 * m;
      pm[4 * m + 0] = pos0[n];
      pm[4 * m + 1] = pos1[n];
      pm[4 * m + 2] = pos0[n + 4096];
      pm[4 * m + 3] = pos1[n + 4096];
    }
    float2 r[16];
#pragma unroll
    for (int m = 0; m < 4; ++m) {
      int n = tid + 1024 * m;
      float2 z0 = a[SW(n)], z1 = a[SW(n + 4096)], z2 = a[SW(n + 8192)], z3 = a[SW(n + 12288)];
      float2 w1, w2, w3; tw3(n, w1, w2, w3);
      bf4i(z0, z1, z2, z3, w1, w2, w3);
      r[4 * m + 0] = z0; r[4 * m + 1] = z1; r[4 * m + 2] = z2; r[4 * m + 3] = z3;
    }
    __syncthreads();   // all pass-G inputs consumed before overwriting
#pragma unroll
    for (int m = 0; m < 4; ++m) {
      int n = tid + 1024 * m;
      a[SW(n + 8192)]  = r[4 * m + 2];   // z[n+8192]
      a[SW(n + 12288)] = r[4 * m + 3];   // z[n+12288]
    }
    __syncthreads();
#pragma unroll
    for (int m = 0; m < 4; ++m) {
      int n = tid + 1024 * m;
      float2 zA = r[4 * m + 0];                 // z[n]
      float2 zB = r[4 * m + 1];                 // z[n+4096]
      float2 wA = a[SW(n + 8193)];              // z[n+8193]
      float2 wB = (n < 4095) ? a[SW(n + 12289)] : make_float2(0.0f, 0.0f);
      float y0A = zA.x + wA.x, y1A = zA.y + wA.y;
      float y0B = zB.x + wB.x, y1B = zB.y + wB.y;
      o0[n]        = (pm[4 * m + 0] != -1) ? y0A : 0.0f;
      o1[n]        = (pm[4 * m + 1] != -1) ? y1A : 0.0f;
      o0[n + 4096] = (pm[4 * m + 2] != -1) ? y0B : 0.0f;
      o1[n + 4096] = (pm[4 * m + 3] != -1) ? y1B : 0.0f;
    }
  }
}

extern "C" void kernel_launch(void* const* d_in, const int* in_sizes, int n_in,
                              void* d_out, int out_size, void* d_ws, size_t ws_size,
                              hipStream_t stream) {
  const float* inputs    = (const float*)d_in[0];   // (B,H,D,L) fp32
  const float* filters   = (const float*)d_in[1];   // (H,D,L) fp32
  const float* bias      = (const float*)d_in[2];   // (D,) fp32
  const int*   positions = (const int*)d_in[3];     // (B,L) int32
  float* outp = (float*)d_out;                      // (B,H,D,L) fp32
  float2* G = (float2*)d_ws;                        // HD * 16384 complex = 128 MiB

  hipLaunchKernelGGL(filt_fft_kernel, dim3(HD), dim3(NT), 0, stream, filters, bias, G);
  hipLaunchKernelGGL(conv_fft_kernel, dim3(HD * 2), dim3(NT), 0, stream,
                     inputs, G, positions, outp);
}